// Round 1
// baseline (697.094 us; speedup 1.0000x reference)
//
#include <hip/hip_runtime.h>

#define T_STEPS 120
#define NF_IN   180
#define H_DIM   128
#define G_DIM   512
#define F_PAD   200   // LDS row stride for FC staging (bytes: 400, 16B-aligned)
#define K_FC    192   // padded K for FC mfma (6 chunks of 32)

typedef __attribute__((ext_vector_type(8))) short short8;
typedef __attribute__((ext_vector_type(4))) float f32x4;

__device__ __forceinline__ f32x4 mfma16(short8 a, short8 b, f32x4 c) {
    return __builtin_amdgcn_mfma_f32_16x16x32_bf16(a, b, c, 0, 0, 0);
}

__device__ __forceinline__ short f2bf(float x) {
    union { float f; unsigned u; } v; v.f = x;
    unsigned r = v.u + 0x7fffu + ((v.u >> 16) & 1u);
    return (short)(r >> 16);
}

__device__ __forceinline__ float sigm(float x) {
    return __builtin_amdgcn_rcpf(1.f + __expf(-x));
}
__device__ __forceinline__ float tanh_f(float x) {
    return 1.f - 2.f * __builtin_amdgcn_rcpf(1.f + __expf(2.f * x));
}

// ---------------- K1: weight prep (BN fold + bf16 conversion) ----------------
__global__ void prep_kernel(
    const float* __restrict__ fc_w, const float* __restrict__ fc_b,
    const float* __restrict__ bn_g, const float* __restrict__ bn_b,
    const float* __restrict__ bn_mean, const float* __restrict__ bn_var,
    const float* __restrict__ wih0, const float* __restrict__ whh0,
    const float* __restrict__ bih0, const float* __restrict__ bhh0,
    const float* __restrict__ wih1, const float* __restrict__ whh1,
    const float* __restrict__ bih1, const float* __restrict__ bhh1,
    short* __restrict__ fcw_o, float* __restrict__ fcb_o,
    float* __restrict__ bias0_o, float* __restrict__ bias1_o,
    short* __restrict__ wih0_o, short* __restrict__ whh0_o,
    short* __restrict__ wih1_o, short* __restrict__ whh1_o)
{
    int tid = blockIdx.x * blockDim.x + threadIdx.x;
    int stride = gridDim.x * blockDim.x;
    for (int i = tid; i < H_DIM * K_FC; i += stride) {
        int h = i / K_FC, f = i % K_FC;
        float s = bn_g[h] * rsqrtf(bn_var[h] + 1e-5f);
        float v = (f < NF_IN) ? fc_w[h * NF_IN + f] * s : 0.f;
        fcw_o[i] = f2bf(v);
    }
    for (int i = tid; i < H_DIM; i += stride) {
        float s = bn_g[i] * rsqrtf(bn_var[i] + 1e-5f);
        fcb_o[i] = (fc_b[i] - bn_mean[i]) * s + bn_b[i];
    }
    for (int i = tid; i < G_DIM; i += stride) {
        bias0_o[i] = bih0[i] + bhh0[i];
        bias1_o[i] = bih1[i] + bhh1[i];
    }
    for (int i = tid; i < G_DIM * H_DIM; i += stride) {
        wih0_o[i] = f2bf(wih0[i]); whh0_o[i] = f2bf(whh0[i]);
        wih1_o[i] = f2bf(wih1[i]); whh1_o[i] = f2bf(whh1[i]);
    }
}

// ---------------- K2: fused FC + BN + LeakyReLU (MFMA) ----------------
// One block per batch element. x[b]: (180,120) f32 -> h0[b]: (120,128) bf16
__global__ __launch_bounds__(256) void fc_kernel(
    const float* __restrict__ x, const short* __restrict__ fcw,
    const float* __restrict__ fcb, short* __restrict__ h0)
{
    __shared__ short xs[128 * F_PAD];   // 51200 B; also reused as output staging
    const int b = blockIdx.x;
    const int tid = threadIdx.x;

    // zero LDS (covers f>=180 and t>=120 padding)
    for (int i = tid; i < 128 * F_PAD / 2; i += 256) ((unsigned*)xs)[i] = 0u;
    __syncthreads();

    // load + transpose x[b] (f-major) -> xs[t][f] bf16
    const float* xb = x + (size_t)b * (NF_IN * T_STEPS);
    for (int i = tid; i < (NF_IN * T_STEPS / 4); i += 256) {
        int f = i / 30, t4 = (i % 30) * 4;
        float4 v = *(const float4*)(xb + f * T_STEPS + t4);
        xs[(t4 + 0) * F_PAD + f] = f2bf(v.x);
        xs[(t4 + 1) * F_PAD + f] = f2bf(v.y);
        xs[(t4 + 2) * F_PAD + f] = f2bf(v.z);
        xs[(t4 + 3) * F_PAD + f] = f2bf(v.w);
    }
    __syncthreads();

    const int wave = tid >> 6, lane = tid & 63;
    const int m16 = lane & 15, q = lane >> 4;

    // A-fragments: wave handles M-tiles {2w, 2w+1}
    short8 af[2][6];
#pragma unroll
    for (int mi = 0; mi < 2; ++mi) {
        int t = (wave * 2 + mi) * 16 + m16;
#pragma unroll
        for (int kc = 0; kc < 6; ++kc)
            af[mi][kc] = *(const short8*)(xs + t * F_PAD + kc * 32 + q * 8);
    }

    float fcb_v[8];
#pragma unroll
    for (int nt = 0; nt < 8; ++nt) fcb_v[nt] = fcb[nt * 16 + m16];

    f32x4 acc[2][8];
#pragma unroll
    for (int mi = 0; mi < 2; ++mi)
#pragma unroll
        for (int nt = 0; nt < 8; ++nt) acc[mi][nt] = (f32x4){0.f, 0.f, 0.f, 0.f};

#pragma unroll
    for (int nt = 0; nt < 8; ++nt) {
        short8 bf[6];
#pragma unroll
        for (int kc = 0; kc < 6; ++kc)
            bf[kc] = *(const short8*)(fcw + (nt * 16 + m16) * K_FC + kc * 32 + q * 8);
#pragma unroll
        for (int mi = 0; mi < 2; ++mi)
#pragma unroll
            for (int kc = 0; kc < 6; ++kc)
                acc[mi][nt] = mfma16(af[mi][kc], bf[kc], acc[mi][nt]);
    }
    __syncthreads();

    // epilogue: bias + LeakyReLU -> bf16 staging (reuse xs), then coalesced store
    short* outs = xs;
#pragma unroll
    for (int mi = 0; mi < 2; ++mi)
#pragma unroll
        for (int nt = 0; nt < 8; ++nt)
#pragma unroll
            for (int r = 0; r < 4; ++r) {
                int t = (wave * 2 + mi) * 16 + q * 4 + r;
                int h = nt * 16 + m16;
                float v = acc[mi][nt][r] + fcb_v[nt];
                v = (v >= 0.f) ? v : 0.01f * v;
                outs[t * H_DIM + h] = f2bf(v);
            }
    __syncthreads();

    unsigned* dst = (unsigned*)h0 + (size_t)b * (T_STEPS * H_DIM / 2);
    const unsigned* srcs = (const unsigned*)outs;
    for (int i = tid; i < T_STEPS * H_DIM / 2; i += 256) dst[i] = srcs[i];
}

// ---------------- K4: one LSTM layer, fused input-proj + recurrence ----------------
// grid = B/8 blocks, 512 threads (8 waves). Waves 0-3: recurrent (whh in VGPRs),
// waves 4-7: producers (wih in VGPRs) computing next step's input projection.
// Layer 0 runs in-place (h_out == h_in is safe: t+1 read precedes t+1 write).
__global__ __launch_bounds__(512, 2) void lstm_kernel(
    const short* h_in,               // (B,T,128) bf16
    const short* __restrict__ wih,   // (512,128) bf16
    const short* __restrict__ whh,   // (512,128) bf16
    const float* __restrict__ bias,  // 512 (bih+bhh)
    short* h_out,                    // (B,T,128) bf16 or null
    float* __restrict__ fout)        // (B,128) f32 or null
{
    __shared__ short h_lds[16 * H_DIM];       // 4 KB  (rows 8-15 stay zero)
    __shared__ float gates_lds[8 * G_DIM];    // 16 KB (raw recurrent part)
    __shared__ float xp_lds[2][8 * G_DIM];    // 32 KB (input proj + bias, dbuf)

    const int tid = threadIdx.x;
    const int wave = tid >> 6, lane = tid & 63;
    const int m16 = lane & 15, q = lane >> 4;
    const int b0 = blockIdx.x * 8;
    const bool is_prod = wave >= 4;
    const int slice = (wave & 3) * 128;   // gate slice: wave0=i, 1=f, 2=g, 3=o

    for (int i = tid; i < 16 * H_DIM / 2; i += 512) ((unsigned*)h_lds)[i] = 0u;

    // weight fragments in registers (128 VGPRs/lane)
    const short* W = is_prod ? wih : whh;
    short8 wf[8][4];
#pragma unroll
    for (int nt = 0; nt < 8; ++nt)
#pragma unroll
        for (int kc = 0; kc < 4; ++kc)
            wf[nt][kc] = *(const short8*)(W + (slice + nt * 16 + m16) * H_DIM + kc * 32 + q * 8);

    float bias_v[8];
#pragma unroll
    for (int nt = 0; nt < 8; ++nt) bias_v[nt] = bias[slice + nt * 16 + m16];

    const int urow = wave & 7;            // update phase: row = tid/64
    const int ud = (lane) * 2;            // 2 consecutive h-dims
    float c0 = 0.f, c1 = 0.f;

    auto producer = [&](int t1, int buf) {
        short8 af[4];
        int m = (m16 < 8) ? m16 : 0;      // clamp padded rows (data unused)
        const short* src = h_in + ((size_t)(b0 + m) * T_STEPS + t1) * H_DIM + q * 8;
#pragma unroll
        for (int kc = 0; kc < 4; ++kc) af[kc] = *(const short8*)(src + kc * 32);
#pragma unroll
        for (int nt = 0; nt < 8; ++nt) {
            f32x4 acc = (f32x4){bias_v[nt], bias_v[nt], bias_v[nt], bias_v[nt]};
#pragma unroll
            for (int kc = 0; kc < 4; ++kc) acc = mfma16(af[kc], wf[nt][kc], acc);
            if (q < 2) {
#pragma unroll
                for (int r = 0; r < 4; ++r)
                    xp_lds[buf][(q * 4 + r) * G_DIM + slice + nt * 16 + m16] = acc[r];
            }
        }
    };

    if (is_prod) producer(0, 0);   // prologue: xp for t=0
    __syncthreads();

    for (int t = 0; t < T_STEPS; ++t) {
        if (!is_prod) {
            // recurrent matmul on h(t-1) from LDS
            short8 af[4];
#pragma unroll
            for (int kc = 0; kc < 4; ++kc)
                af[kc] = *(const short8*)(h_lds + m16 * H_DIM + kc * 32 + q * 8);
#pragma unroll
            for (int nt = 0; nt < 8; ++nt) {
                f32x4 acc = (f32x4){0.f, 0.f, 0.f, 0.f};
#pragma unroll
                for (int kc = 0; kc < 4; ++kc) acc = mfma16(af[kc], wf[nt][kc], acc);
                if (q < 2) {
#pragma unroll
                    for (int r = 0; r < 4; ++r)
                        gates_lds[(q * 4 + r) * G_DIM + slice + nt * 16 + m16] = acc[r];
                }
            }
        } else if (t + 1 < T_STEPS) {
            producer(t + 1, (t + 1) & 1);
        }
        __syncthreads();

        // update phase: all 512 threads, 2 h-dims each
        {
            const float* gb = gates_lds;
            const float* xb = xp_lds[t & 1];
            int base = urow * G_DIM + ud;
            float2 ri = *(const float2*)(gb + base);
            float2 rf = *(const float2*)(gb + base + 128);
            float2 rg = *(const float2*)(gb + base + 256);
            float2 ro = *(const float2*)(gb + base + 384);
            float2 xi = *(const float2*)(xb + base);
            float2 xf = *(const float2*)(xb + base + 128);
            float2 xg = *(const float2*)(xb + base + 256);
            float2 xo = *(const float2*)(xb + base + 384);
            float i0 = sigm(ri.x + xi.x), i1 = sigm(ri.y + xi.y);
            float ff0 = sigm(rf.x + xf.x), ff1 = sigm(rf.y + xf.y);
            float g0 = tanh_f(rg.x + xg.x), g1 = tanh_f(rg.y + xg.y);
            float o0 = sigm(ro.x + xo.x), o1 = sigm(ro.y + xo.y);
            c0 = ff0 * c0 + i0 * g0;
            c1 = ff1 * c1 + i1 * g1;
            float hh0 = o0 * tanh_f(c0);
            float hh1 = o1 * tanh_f(c1);
            unsigned packed = (unsigned)(unsigned short)f2bf(hh0) |
                              ((unsigned)(unsigned short)f2bf(hh1) << 16);
            *(unsigned*)(h_lds + urow * H_DIM + ud) = packed;
            if (h_out)
                *(unsigned*)(h_out + ((size_t)(b0 + urow) * T_STEPS + t) * H_DIM + ud) = packed;
            if (fout && t == T_STEPS - 1) {
                float2 hv; hv.x = hh0; hv.y = hh1;
                *(float2*)(fout + (size_t)(b0 + urow) * H_DIM + ud) = hv;
            }
        }
        __syncthreads();
    }
}

// ---------------- launch ----------------
static constexpr size_t OFF_FCW  = 0;        // 128*192*2 = 49152
static constexpr size_t OFF_FCB  = 49152;    // 128*4
static constexpr size_t OFF_B0   = 49664;    // 512*4
static constexpr size_t OFF_B1   = 51712;    // 512*4
static constexpr size_t OFF_WIH0 = 53760;    // 512*128*2
static constexpr size_t OFF_WHH0 = 184832;
static constexpr size_t OFF_WIH1 = 315904;
static constexpr size_t OFF_WHH1 = 446976;
static constexpr size_t OFF_BUFA = 578048;   // B*T*128*2 = 62914560

extern "C" void kernel_launch(void* const* d_in, const int* in_sizes, int n_in,
                              void* d_out, int out_size, void* d_ws, size_t ws_size,
                              hipStream_t stream) {
    const float* x       = (const float*)d_in[0];
    const float* fc_w    = (const float*)d_in[1];
    const float* fc_b    = (const float*)d_in[2];
    const float* bn_g    = (const float*)d_in[3];
    const float* bn_b    = (const float*)d_in[4];
    const float* bn_mean = (const float*)d_in[5];
    const float* bn_var  = (const float*)d_in[6];
    const float* wih0    = (const float*)d_in[7];
    const float* whh0    = (const float*)d_in[8];
    const float* bih0    = (const float*)d_in[9];
    const float* bhh0    = (const float*)d_in[10];
    const float* wih1    = (const float*)d_in[11];
    const float* whh1    = (const float*)d_in[12];
    const float* bih1    = (const float*)d_in[13];
    const float* bhh1    = (const float*)d_in[14];

    const int B = in_sizes[0] / (NF_IN * T_STEPS);   // 2048

    char* ws = (char*)d_ws;
    short* fcw   = (short*)(ws + OFF_FCW);
    float* fcb   = (float*)(ws + OFF_FCB);
    float* bias0 = (float*)(ws + OFF_B0);
    float* bias1 = (float*)(ws + OFF_B1);
    short* wih0b = (short*)(ws + OFF_WIH0);
    short* whh0b = (short*)(ws + OFF_WHH0);
    short* wih1b = (short*)(ws + OFF_WIH1);
    short* whh1b = (short*)(ws + OFF_WHH1);
    short* bufA  = (short*)(ws + OFF_BUFA);

    prep_kernel<<<256, 256, 0, stream>>>(
        fc_w, fc_b, bn_g, bn_b, bn_mean, bn_var,
        wih0, whh0, bih0, bhh0, wih1, whh1, bih1, bhh1,
        fcw, fcb, bias0, bias1, wih0b, whh0b, wih1b, whh1b);

    fc_kernel<<<B, 256, 0, stream>>>(x, fcw, fcb, bufA);

    // layer 0: in-place on bufA
    lstm_kernel<<<B / 8, 512, 0, stream>>>(bufA, wih0b, whh0b, bias0, bufA, nullptr);
    // layer 1: final hidden only
    lstm_kernel<<<B / 8, 512, 0, stream>>>(bufA, wih1b, whh1b, bias1, nullptr, (float*)d_out);
}

// Round 2
// 654.612 us; speedup vs baseline: 1.0649x; 1.0649x over previous
//
#include <hip/hip_runtime.h>

#define T_STEPS 120
#define NF_IN   180
#define H_DIM   128
#define G_DIM   512
#define K_FC    192
#define HP      136          // padded h_lds row stride (shorts): 272 B == 4 mod 32 banks
#define XP_TILE 4096         // floats per xp buffer (32 tiles * 16 m * 8 rows)

typedef __attribute__((ext_vector_type(8))) short short8;
typedef __attribute__((ext_vector_type(4))) float f32x4;

__device__ __forceinline__ f32x4 mfma16(short8 a, short8 b, f32x4 c) {
    return __builtin_amdgcn_mfma_f32_16x16x32_bf16(a, b, c, 0, 0, 0);
}

__device__ __forceinline__ short f2bf(float x) {
    union { float f; unsigned u; } v; v.f = x;
    unsigned r = v.u + 0x7fffu + ((v.u >> 16) & 1u);
    return (short)(r >> 16);
}

__device__ __forceinline__ float sigm(float x) {
    return __builtin_amdgcn_rcpf(1.f + __expf(-x));
}
__device__ __forceinline__ float tanh_f(float x) {
    return 1.f - 2.f * __builtin_amdgcn_rcpf(1.f + __expf(2.f * x));
}

// ---------------- K1: weight prep (BN fold + bf16 conversion) ----------------
__global__ void prep_kernel(
    const float* __restrict__ fc_w, const float* __restrict__ fc_b,
    const float* __restrict__ bn_g, const float* __restrict__ bn_b,
    const float* __restrict__ bn_mean, const float* __restrict__ bn_var,
    const float* __restrict__ wih0, const float* __restrict__ whh0,
    const float* __restrict__ bih0, const float* __restrict__ bhh0,
    const float* __restrict__ wih1, const float* __restrict__ whh1,
    const float* __restrict__ bih1, const float* __restrict__ bhh1,
    short* __restrict__ fcw_o, float* __restrict__ fcb_o,
    float* __restrict__ bias0_o, float* __restrict__ bias1_o,
    short* __restrict__ wih0_o, short* __restrict__ whh0_o,
    short* __restrict__ wih1_o, short* __restrict__ whh1_o)
{
    int tid = blockIdx.x * blockDim.x + threadIdx.x;
    int stride = gridDim.x * blockDim.x;
    for (int i = tid; i < H_DIM * K_FC; i += stride) {
        int h = i / K_FC, f = i % K_FC;
        float s = bn_g[h] * rsqrtf(bn_var[h] + 1e-5f);
        float v = (f < NF_IN) ? fc_w[h * NF_IN + f] * s : 0.f;
        fcw_o[i] = f2bf(v);
    }
    for (int i = tid; i < H_DIM; i += stride) {
        float s = bn_g[i] * rsqrtf(bn_var[i] + 1e-5f);
        fcb_o[i] = (fc_b[i] - bn_mean[i]) * s + bn_b[i];
    }
    for (int i = tid; i < G_DIM; i += stride) {
        bias0_o[i] = bih0[i] + bhh0[i];
        bias1_o[i] = bih1[i] + bhh1[i];
    }
    for (int i = tid; i < G_DIM * H_DIM; i += stride) {
        wih0_o[i] = f2bf(wih0[i]); whh0_o[i] = f2bf(whh0[i]);
        wih1_o[i] = f2bf(wih1[i]); whh1_o[i] = f2bf(whh1[i]);
    }
}

// ---------------- K2: fused FC + BN + LeakyReLU (MFMA, direct global A-loads) ---
// One block per batch element. x[b]: (180,120) f32 -> xfc[b]: (120,128) bf16
__global__ __launch_bounds__(256) void fc_kernel(
    const float* __restrict__ x, const short* __restrict__ fcw,
    const float* __restrict__ fcb, short* __restrict__ xfc)
{
    __shared__ short outs[120 * 132];   // padded staging, 31680 B
    const int b = blockIdx.x;
    const int tid = threadIdx.x;
    const int wave = tid >> 6, lane = tid & 63;
    const int m16 = lane & 15, q = lane >> 4;

    // A-fragments loaded directly from global x (strided 4B, full-cacheline use)
    short8 af[2][6];
#pragma unroll
    for (int mi = 0; mi < 2; ++mi) {
        int t = (wave * 2 + mi) * 16 + m16;
        if (t > 119) t = 119;
        const float* xb = x + (size_t)b * (NF_IN * T_STEPS) + (size_t)q * 8 * T_STEPS + t;
#pragma unroll
        for (int kc = 0; kc < 6; ++kc) {
            union { short s[8]; short8 v; } u;
#pragma unroll
            for (int j = 0; j < 8; ++j) {
                int f = kc * 32 + q * 8 + j;
                float val = (f < NF_IN) ? xb[(kc * 32 + j) * T_STEPS] : 0.f;
                u.s[j] = f2bf(val);
            }
            af[mi][kc] = u.v;
        }
    }

    float fcb_v[8];
#pragma unroll
    for (int nt = 0; nt < 8; ++nt) fcb_v[nt] = fcb[nt * 16 + m16];

    f32x4 acc[2][8];
#pragma unroll
    for (int mi = 0; mi < 2; ++mi)
#pragma unroll
        for (int nt = 0; nt < 8; ++nt) acc[mi][nt] = (f32x4){0.f, 0.f, 0.f, 0.f};

#pragma unroll
    for (int nt = 0; nt < 8; ++nt) {
        short8 bf[6];
#pragma unroll
        for (int kc = 0; kc < 6; ++kc)
            bf[kc] = *(const short8*)(fcw + (nt * 16 + m16) * K_FC + kc * 32 + q * 8);
#pragma unroll
        for (int mi = 0; mi < 2; ++mi)
#pragma unroll
            for (int kc = 0; kc < 6; ++kc)
                acc[mi][nt] = mfma16(af[mi][kc], bf[kc], acc[mi][nt]);
    }

    // epilogue: bias + LeakyReLU -> padded bf16 staging, then coalesced store
#pragma unroll
    for (int mi = 0; mi < 2; ++mi)
#pragma unroll
        for (int nt = 0; nt < 8; ++nt)
#pragma unroll
            for (int r = 0; r < 4; ++r) {
                int t = (wave * 2 + mi) * 16 + q * 4 + r;
                int h = nt * 16 + m16;
                float v = acc[mi][nt][r] + fcb_v[nt];
                v = (v >= 0.f) ? v : 0.01f * v;
                if (t < 120) outs[t * 132 + h] = f2bf(v);
            }
    __syncthreads();

    unsigned* dst = (unsigned*)xfc + (size_t)b * (T_STEPS * H_DIM / 2);
    const unsigned* srcs = (const unsigned*)outs;
    for (int i = tid; i < T_STEPS * H_DIM / 2; i += 256) {
        int t = i >> 6, c2 = i & 63;
        dst[i] = srcs[t * 66 + c2];
    }
}

// ---------------- K3: one LSTM layer -----------------------------------------
// grid = B/8, 512 threads. Waves 0-3: recurrent matmul + in-register gate/cell
// update (each wave owns ALL 4 gates for a 32-dim slice -> no gate LDS gather,
// one barrier per step). Waves 4-7: producers computing next step's input
// projection into C-layout LDS (b128 writes). whh/wih held in VGPRs (128/lane).
__global__ __launch_bounds__(512, 2) void lstm_kernel(
    const short* h_in,               // (B,T,128) bf16 (layer0: xfc)
    const short* __restrict__ wih,   // (512,128) bf16
    const short* __restrict__ whh,   // (512,128) bf16
    const float* __restrict__ bias,  // 512 (bih+bhh)
    short* h_out,                    // (B,T,128) bf16 or null (may alias h_in)
    float* __restrict__ fout)        // (B,128) f32 or null
{
    __shared__ short h_lds[2 * 8 * HP];     // 4352 B, padded rows
    __shared__ float xp_lds[2 * XP_TILE];   // 32 KB

    const int tid = threadIdx.x;
    const int wave = tid >> 6, lane = tid & 63;
    const int q = lane >> 4, m16 = lane & 15, m8 = m16 & 7;
    const int qv = q & 1;                   // clamped row-group for dup lanes
    const int b0 = blockIdx.x * 8;
    const bool cons = wave < 4;
    const int d = wave & 3;                 // 32-dim slice index

    for (int i = tid; i < 8 * HP; i += 512) ((unsigned*)h_lds)[i] = 0u;

    // weights: 4 gates x 2 subtiles x 4 k-chunks = 128 VGPR/lane
    const short* W = cons ? whh : wih;
    short8 wf[4][2][4];
    float bias_v[4][2];
#pragma unroll
    for (int g = 0; g < 4; ++g)
#pragma unroll
        for (int j = 0; j < 2; ++j) {
            int n = g * 128 + d * 32 + j * 16 + m16;
            bias_v[g][j] = bias[n];
#pragma unroll
            for (int kc = 0; kc < 4; ++kc)
                wf[g][j][kc] = *(const short8*)(W + n * H_DIM + kc * 32 + q * 8);
        }

    float c[2][4];
#pragma unroll
    for (int j = 0; j < 2; ++j)
#pragma unroll
        for (int r = 0; r < 4; ++r) c[j][r] = 0.f;

    auto prod = [&](int t) {
        const short* src = h_in + ((size_t)(b0 + m8) * T_STEPS + t) * H_DIM + q * 8;
        short8 ax[4];
#pragma unroll
        for (int kc = 0; kc < 4; ++kc) ax[kc] = *(const short8*)(src + kc * 32);
        float* xpb = xp_lds + (t & 1) * XP_TILE;
#pragma unroll
        for (int g = 0; g < 4; ++g)
#pragma unroll
            for (int j = 0; j < 2; ++j) {
                float bv = bias_v[g][j];
                f32x4 acc = (f32x4){bv, bv, bv, bv};
#pragma unroll
                for (int kc = 0; kc < 4; ++kc) acc = mfma16(ax[kc], wf[g][j][kc], acc);
                if (q < 2)
                    *(f32x4*)(xpb + ((d * 8 + g * 2 + j) * 16 + m16) * 8 + q * 4) = acc;
            }
    };

    if (!cons) prod(0);
    __syncthreads();

    for (int s = 0; s < T_STEPS; ++s) {
        if (cons) {
            // recurrent matmul on h(s-1)
            const short* hb = h_lds + ((s + 1) & 1) * (8 * HP) + m8 * HP + q * 8;
            short8 ar[4];
#pragma unroll
            for (int kc = 0; kc < 4; ++kc) ar[kc] = *(const short8*)(hb + kc * 32);
            f32x4 racc[4][2];
#pragma unroll
            for (int g = 0; g < 4; ++g)
#pragma unroll
                for (int j = 0; j < 2; ++j) {
                    f32x4 acc = (f32x4){0.f, 0.f, 0.f, 0.f};
#pragma unroll
                    for (int kc = 0; kc < 4; ++kc) acc = mfma16(ar[kc], wf[g][j][kc], acc);
                    racc[g][j] = acc;
                }
            const float* xpb = xp_lds + (s & 1) * XP_TILE;
            short* hw = h_lds + (s & 1) * (8 * HP);
#pragma unroll
            for (int j = 0; j < 2; ++j) {
                f32x4 xv[4];
#pragma unroll
                for (int g = 0; g < 4; ++g)
                    xv[g] = *(const f32x4*)(xpb + ((d * 8 + g * 2 + j) * 16 + m16) * 8 + qv * 4);
#pragma unroll
                for (int r = 0; r < 4; ++r) {
                    float iv = sigm(racc[0][j][r] + xv[0][r]);
                    float fv = sigm(racc[1][j][r] + xv[1][r]);
                    float gv = tanh_f(racc[2][j][r] + xv[2][r]);
                    float ov = sigm(racc[3][j][r] + xv[3][r]);
                    float cc = fv * c[j][r] + iv * gv;
                    c[j][r] = cc;
                    float hv = ov * tanh_f(cc);
                    if (q < 2) {
                        hw[(q * 4 + r) * HP + d * 32 + j * 16 + m16] = f2bf(hv);
                        if (fout != nullptr && s == T_STEPS - 1)
                            fout[(size_t)(b0 + q * 4 + r) * H_DIM + d * 32 + j * 16 + m16] = hv;
                    }
                }
            }
        } else {
            if (s + 1 < T_STEPS) prod(s + 1);
        }
        // coalesced export of h(s-1) (written one barrier ago)
        if (h_out != nullptr && s >= 1) {
            int row = tid >> 6, c2 = tid & 63;
            unsigned v = ((const unsigned*)h_lds)[((s + 1) & 1) * (4 * HP) + row * (HP / 2) + c2];
            ((unsigned*)h_out)[((size_t)(b0 + row) * T_STEPS + (s - 1)) * (H_DIM / 2) + c2] = v;
        }
        __syncthreads();
    }
    if (h_out != nullptr) {   // tail: h(T-1) lives in buffer (T-1)&1 = 1
        int row = tid >> 6, c2 = tid & 63;
        unsigned v = ((const unsigned*)h_lds)[1 * (4 * HP) + row * (HP / 2) + c2];
        ((unsigned*)h_out)[((size_t)(b0 + row) * T_STEPS + (T_STEPS - 1)) * (H_DIM / 2) + c2] = v;
    }
}

// ---------------- launch ----------------
static constexpr size_t OFF_FCW  = 0;        // 128*192*2 = 49152
static constexpr size_t OFF_FCB  = 49152;    // 128*4
static constexpr size_t OFF_B0   = 49664;    // 512*4
static constexpr size_t OFF_B1   = 51712;    // 512*4
static constexpr size_t OFF_WIH0 = 53760;    // 512*128*2
static constexpr size_t OFF_WHH0 = 184832;
static constexpr size_t OFF_WIH1 = 315904;
static constexpr size_t OFF_WHH1 = 446976;
static constexpr size_t OFF_BUFA = 578048;   // B*T*128*2 = 62914560

extern "C" void kernel_launch(void* const* d_in, const int* in_sizes, int n_in,
                              void* d_out, int out_size, void* d_ws, size_t ws_size,
                              hipStream_t stream) {
    const float* x       = (const float*)d_in[0];
    const float* fc_w    = (const float*)d_in[1];
    const float* fc_b    = (const float*)d_in[2];
    const float* bn_g    = (const float*)d_in[3];
    const float* bn_b    = (const float*)d_in[4];
    const float* bn_mean = (const float*)d_in[5];
    const float* bn_var  = (const float*)d_in[6];
    const float* wih0    = (const float*)d_in[7];
    const float* whh0    = (const float*)d_in[8];
    const float* bih0    = (const float*)d_in[9];
    const float* bhh0    = (const float*)d_in[10];
    const float* wih1    = (const float*)d_in[11];
    const float* whh1    = (const float*)d_in[12];
    const float* bih1    = (const float*)d_in[13];
    const float* bhh1    = (const float*)d_in[14];

    const int B = in_sizes[0] / (NF_IN * T_STEPS);   // 2048

    char* ws = (char*)d_ws;
    short* fcw   = (short*)(ws + OFF_FCW);
    float* fcb   = (float*)(ws + OFF_FCB);
    float* bias0 = (float*)(ws + OFF_B0);
    float* bias1 = (float*)(ws + OFF_B1);
    short* wih0b = (short*)(ws + OFF_WIH0);
    short* whh0b = (short*)(ws + OFF_WHH0);
    short* wih1b = (short*)(ws + OFF_WIH1);
    short* whh1b = (short*)(ws + OFF_WHH1);
    short* bufA  = (short*)(ws + OFF_BUFA);

    prep_kernel<<<256, 256, 0, stream>>>(
        fc_w, fc_b, bn_g, bn_b, bn_mean, bn_var,
        wih0, whh0, bih0, bhh0, wih1, whh1, bih1, bhh1,
        fcw, fcb, bias0, bias1, wih0b, whh0b, wih1b, whh1b);

    fc_kernel<<<B, 256, 0, stream>>>(x, fcw, fcb, bufA);

    // layer 0: in-place on bufA (write of t=s-1 trails read of t=s+1)
    lstm_kernel<<<B / 8, 512, 0, stream>>>(bufA, wih0b, whh0b, bias0, bufA, nullptr);
    // layer 1: final hidden only
    lstm_kernel<<<B / 8, 512, 0, stream>>>(bufA, wih1b, whh1b, bias1, nullptr, (float*)d_out);
}